// Round 14
// baseline (271.748 us; speedup 1.0000x reference)
//
#include <hip/hip_runtime.h>
#include <math.h>

#define N_PTS 4096
#define DD 1024
#define DL 64
#define NEDGE (N_PTS - 1)
#define B_ROUNDS 12
#define NT 32  // 4096/128 tiles per dim

typedef __attribute__((ext_vector_type(8))) short short8;
typedef __attribute__((ext_vector_type(4))) float floatx4;
typedef __attribute__((ext_vector_type(4))) unsigned short ushortx4;

__device__ __forceinline__ unsigned short f2bf(float f) {
  unsigned u = __float_as_uint(f);
  u = u + 0x7FFFu + ((u >> 16) & 1u);  // RNE
  return (unsigned short)(u >> 16);
}

// ---- fused: ae_loss + sqnorms + bf16 converts (blocks [0,4096) data, [4096,5120) latent)
__global__ __launch_bounds__(256) void ae_sql_kernel(const float* __restrict__ yt,
                                                     const float* __restrict__ yp,
                                                     const float* __restrict__ lat,
                                                     float* __restrict__ out,
                                                     float* __restrict__ sqD,
                                                     float* __restrict__ sqL,
                                                     unsigned short* __restrict__ Xb,
                                                     unsigned short* __restrict__ Lb) {
  int tid = threadIdx.x;
  if (blockIdx.x < N_PTS) {
    int row = blockIdx.x;
    const float4* a = (const float4*)(yt + (size_t)row * DD);
    const float4* b = (const float4*)(yp + (size_t)row * DD);
    float4 va = a[tid], vb = b[tid];
    ushortx4 o = {f2bf(va.x), f2bf(va.y), f2bf(va.z), f2bf(va.w)};
    *(ushortx4*)(Xb + (size_t)row * DD + tid * 4) = o;
    float e0 = va.x - vb.x, e1 = va.y - vb.y, e2 = va.z - vb.z, e3 = va.w - vb.w;
    float se = e0 * e0 + e1 * e1 + e2 * e2 + e3 * e3;
    float ss = va.x * va.x + va.y * va.y + va.z * va.z + va.w * va.w;
    for (int off = 32; off > 0; off >>= 1) {
      se += __shfl_down(se, off);
      ss += __shfl_down(ss, off);
    }
    __shared__ float sse[4], sss[4];
    int lane = tid & 63, w = tid >> 6;
    if (lane == 0) { sse[w] = se; sss[w] = ss; }
    __syncthreads();
    if (tid == 0) {
      out[row] = (sse[0] + sse[1] + sse[2] + sse[3]) * (1.0f / DD);
      sqD[row] = sss[0] + sss[1] + sss[2] + sss[3];
    }
  } else {
    int row = (blockIdx.x - N_PTS) * 4 + (tid >> 6);
    int lane = tid & 63;
    float v = lat[(size_t)row * DL + lane];
    Lb[(size_t)row * DL + lane] = f2bf(v);
    float s = v * v;
    for (int off = 32; off > 0; off >>= 1) s += __shfl_down(s, off);
    if (lane == 0) sqL[row] = s;
  }
}

// ------- init (R12-proven) + fused norm + counter zeroing (replaces memset) -------
__global__ __launch_bounds__(256) void boruvka_init(unsigned short* __restrict__ comp,
                                                    unsigned long long* __restrict__ bestKey,
                                                    int* __restrict__ numRoots,
                                                    int* __restrict__ edgeCnt,
                                                    const float* __restrict__ sqD,
                                                    const float* __restrict__ sqL,
                                                    unsigned int* __restrict__ normbits,
                                                    unsigned int* __restrict__ maxbits,
                                                    float* __restrict__ sums) {
  int i = blockIdx.x * 256 + threadIdx.x;
  if (i < N_PTS) {
    comp[i] = (unsigned short)i;
    comp[N_PTS + i] = (unsigned short)i;
    bestKey[i] = ~0ULL;
    bestKey[N_PTS + i] = ~0ULL;
  }
  if (i == 0) {
    numRoots[0] = N_PTS; numRoots[1] = N_PTS;
    edgeCnt[0] = 0; edgeCnt[1] = 0;
    maxbits[0] = 0;
    sums[0] = 0.f; sums[1] = 0.f;
  }
  if (blockIdx.x < 2) {
    const float* s = blockIdx.x ? sqL : sqD;
    int tid = threadIdx.x;
    float m = 0.f;
#pragma unroll
    for (int k = 0; k < 16; ++k) m = fmaxf(m, s[tid + k * 256]);
    for (int off = 32; off > 0; off >>= 1) m = fmaxf(m, __shfl_down(m, off));
    __shared__ float sm[4];
    int lane = tid & 63, w = tid >> 6;
    if (lane == 0) sm[w] = m;
    __syncthreads();
    if (tid == 0)
      normbits[blockIdx.x] = __float_as_uint(fmaxf(fmaxf(sm[0], sm[1]), fmaxf(sm[2], sm[3])));
  }
}

// ---------------- bf16 MFMA distance gemm -> scaled-u16 D-SQUARED matrices ----------
// u16 = d^2 * 65535/(4*maxsq) — monotone in d, so MST selection is unchanged; drops
// 16K sqrts/block from the VALU-bound epilogue and gives FINER resolution near the
// data's distance concentration (delta-d = delta-d2/(2d)). maxbits tracks max d^2.
__global__ __launch_bounds__(256) void dist_mfma(const unsigned short* __restrict__ Xb,
                                                 const unsigned short* __restrict__ Lb,
                                                 const float* __restrict__ sqD,
                                                 const float* __restrict__ sqL,
                                                 unsigned short* __restrict__ dD,
                                                 unsigned short* __restrict__ dL,
                                                 const unsigned int* __restrict__ normbits,
                                                 unsigned int* __restrict__ maxbits) {
  int inst = blockIdx.y;
  const unsigned short* X = inst ? Lb : Xb;
  const float* sq = inst ? sqL : sqD;
  unsigned short* dist = inst ? dL : dD;
  int K = inst ? DL : DD;
  float scale2 = 65535.0f / (4.0f * __uint_as_float(normbits[inst]) + 1e-12f);

  int bi = 0, rem = blockIdx.x, span = NT;  // triangular decode, bi <= bj
  while (rem >= span) { rem -= span; ++bi; --span; }
  int bj = bi + rem;
  int row0 = bi * 128, col0 = bj * 128;

  __shared__ short As[128 * 40];
  __shared__ short Bs[128 * 40];
  int tid = threadIdx.x;
  int wave = tid >> 6, lane = tid & 63;
  int m = lane & 15, q = lane >> 4;
  int rw = (wave >> 1) * 64, cw = (wave & 1) * 64;

  floatx4 acc[4][4];
#pragma unroll
  for (int mi = 0; mi < 4; ++mi)
#pragma unroll
    for (int ni = 0; ni < 4; ++ni) acc[mi][ni] = {0.f, 0.f, 0.f, 0.f};

  int s0 = tid, s1 = tid + 256;
  int r0 = s0 >> 2, p0 = s0 & 3, r1 = s1 >> 2, p1 = s1 & 3;

  for (int k0 = 0; k0 < K; k0 += 32) {
    short8 a0 = *(const short8*)(X + (size_t)(row0 + r0) * K + k0 + p0 * 8);
    short8 a1 = *(const short8*)(X + (size_t)(row0 + r1) * K + k0 + p1 * 8);
    short8 b0 = *(const short8*)(X + (size_t)(col0 + r0) * K + k0 + p0 * 8);
    short8 b1 = *(const short8*)(X + (size_t)(col0 + r1) * K + k0 + p1 * 8);
    __syncthreads();
    *(short8*)&As[r0 * 40 + p0 * 8] = a0;
    *(short8*)&As[r1 * 40 + p1 * 8] = a1;
    *(short8*)&Bs[r0 * 40 + p0 * 8] = b0;
    *(short8*)&Bs[r1 * 40 + p1 * 8] = b1;
    __syncthreads();
    short8 aF[4], bF[4];
#pragma unroll
    for (int mi = 0; mi < 4; ++mi)
      aF[mi] = *(const short8*)&As[(rw + mi * 16 + m) * 40 + q * 8];
#pragma unroll
    for (int ni = 0; ni < 4; ++ni)
      bF[ni] = *(const short8*)&Bs[(cw + ni * 16 + m) * 40 + q * 8];
#pragma unroll
    for (int mi = 0; mi < 4; ++mi)
#pragma unroll
      for (int ni = 0; ni < 4; ++ni)
        acc[mi][ni] = __builtin_amdgcn_mfma_f32_16x16x32_bf16(aF[mi], bF[ni],
                                                              acc[mi][ni], 0, 0, 0);
  }

  float bmax = 0.f;  // max d^2
#pragma unroll
  for (int mi = 0; mi < 4; ++mi) {
    int i0 = row0 + rw + mi * 16 + q * 4;
    float s_i[4] = {sq[i0], sq[i0 + 1], sq[i0 + 2], sq[i0 + 3]};
#pragma unroll
    for (int ni = 0; ni < 4; ++ni) {
      int j = col0 + cw + ni * 16 + m;
      float sj = sq[j];
      ushortx4 tvec;
#pragma unroll
      for (int r = 0; r < 4; ++r) {
        float d2 = s_i[r] + sj - 2.f * acc[mi][ni][r];
        d2 = d2 > 0.f ? d2 : 0.f;
        bmax = fmaxf(bmax, d2);
        unsigned short u = (unsigned short)fminf(d2 * scale2, 65535.0f);
        dist[(size_t)(i0 + r) * N_PTS + j] = u;
        tvec[r] = u;
      }
      *(ushortx4*)&dist[(size_t)j * N_PTS + i0] = tvec;
    }
  }
  if (inst == 0) {
    for (int off = 32; off > 0; off >>= 1) bmax = fmaxf(bmax, __shfl_down(bmax, off));
    __shared__ float bm[4];
    if (lane == 0) bm[wave] = bmax;
    __syncthreads();
    if (tid == 0)
      atomicMax(maxbits, __float_as_uint(fmaxf(fmaxf(bm[0], bm[1]), fmaxf(bm[2], bm[3]))));
  }
}

// Round 0 scan fused with segmin (R11-proven): one 64MB pass -> segKey + plain bestKey.
__global__ __launch_bounds__(256) void boruvka_scan0(const unsigned short* __restrict__ dD,
                                                     const unsigned short* __restrict__ dL,
                                                     unsigned int* __restrict__ segKey,
                                                     unsigned long long* __restrict__ bestKey) {
  int inst = blockIdx.y;
  const unsigned short* dist = inst ? dL : dD;
  unsigned int* segK = segKey + (size_t)inst * N_PTS * 64;
  unsigned long long* bkI = bestKey + (size_t)inst * N_PTS;
  int tid = threadIdx.x, wave = tid >> 6, lane = tid & 63;
  int row = blockIdx.x * 4 + wave;
  const uint4* rowp = (const uint4*)(dist + (size_t)row * N_PTS);
  unsigned mk = 0xFFFFFFFFu, fk = 0xFFFFFFFFu;
  int colbase = lane * 64;
#pragma unroll
  for (int t = 0; t < 8; ++t) {
    uint4 v = rowp[lane * 8 + t];
    unsigned e[8] = {v.x & 0xFFFFu, v.x >> 16, v.y & 0xFFFFu, v.y >> 16,
                     v.z & 0xFFFFu, v.z >> 16, v.w & 0xFFFFu, v.w >> 16};
#pragma unroll
    for (int u = 0; u < 8; ++u) {
      int col = colbase + t * 8 + u;
      unsigned key = (e[u] << 12) | (unsigned)col;
      mk = min(mk, key);
      if (col != row) fk = min(fk, key);
    }
  }
  segK[(size_t)row * 64 + lane] = mk;
#pragma unroll
  for (int off = 32; off > 0; off >>= 1) fk = min(fk, __shfl_xor(fk, off));
  if (lane == 0) {
    unsigned dd16 = fk >> 12;
    int j = (int)(fk & 0xFFFu);
    int lo = row < j ? row : j, hi = row < j ? j : row;
    bkI[row] = ((unsigned long long)dd16 << 24) |
               ((unsigned long long)lo << 12) | (unsigned long long)hi;
  }
}

// Generic scan (rounds >= 1): segment-pruned, one row per wave.
__global__ __launch_bounds__(256) void boruvka_scan(const unsigned short* __restrict__ dD,
                                                    const unsigned short* __restrict__ dL,
                                                    const unsigned int* __restrict__ segKey,
                                                    const unsigned short* __restrict__ comp,
                                                    unsigned long long* __restrict__ bestKey,
                                                    const int* __restrict__ numRoots) {
  int inst = blockIdx.y;
  if (numRoots[inst] <= 1) return;
  const unsigned short* dist = inst ? dL : dD;
  const unsigned int* segK = segKey + (size_t)inst * N_PTS * 64;
  const unsigned short* compI = comp + (size_t)inst * N_PTS;
  unsigned long long* bkI = bestKey + (size_t)inst * N_PTS;
  int tid = threadIdx.x, wave = tid >> 6, lane = tid & 63;

  int row = blockIdx.x * 4 + wave;
  unsigned myc = compI[row];
  unsigned skey = segK[(size_t)row * 64 + lane];
#pragma unroll
  for (int k = 2; k <= 64; k <<= 1)
#pragma unroll
    for (int j = k >> 1; j > 0; j >>= 1) {
      unsigned p = __shfl_xor(skey, j);
      unsigned mn = min(skey, p), mx = max(skey, p);
      skey = (((lane & k) == 0) == ((lane & j) == 0)) ? mn : mx;
    }
  unsigned best = 0xFFFFFFFFu;
  const unsigned short* rowp = dist + (size_t)row * N_PTS;
  int i = 0;
  while (i < 64) {
    unsigned k0 = __shfl(skey, i);
    if (k0 >= best) break;
    unsigned k1 = (i < 63) ? __shfl(skey, i + 1) : 0xFFFFFFFFu;
    int b0 = (int)(k0 & 0xFC0u);
    unsigned d0v = rowp[b0 + lane];
    unsigned c0v = compI[b0 + lane];
    unsigned cand = (c0v != myc) ? ((d0v << 12) | (unsigned)(b0 + lane)) : 0xFFFFFFFFu;
    if (k1 < best) {
      int b1 = (int)(k1 & 0xFC0u);
      unsigned d1v = rowp[b1 + lane];
      unsigned c1v = compI[b1 + lane];
      unsigned c2 = (c1v != myc) ? ((d1v << 12) | (unsigned)(b1 + lane)) : 0xFFFFFFFFu;
      cand = min(cand, c2);
    }
#pragma unroll
    for (int off = 32; off > 0; off >>= 1) cand = min(cand, __shfl_xor(cand, off));
    best = min(best, cand);
    i += 2;
  }
  if (lane == 0 && best != 0xFFFFFFFFu) {
    unsigned dd16 = best >> 12;
    int j = (int)(best & 0xFFFu);
    int lo = row < j ? row : j, hi = row < j ? j : row;
    unsigned long long key40 = ((unsigned long long)dd16 << 24) |
                               ((unsigned long long)lo << 12) | (unsigned long long)hi;
    if (key40 < bkI[myc]) atomicMin(&bkI[myc], key40);  // bkI monotone in-dispatch
  }
}

// Merge (R12-proven): separate dispatch, plain cached loads, wave-shfl prefix
// scan + adaptive pointer jumping. One block per instance, 1024 threads.
__global__ __launch_bounds__(1024) void boruvka_merge(unsigned short* __restrict__ comp,
                                                      unsigned long long* __restrict__ bestKey,
                                                      int* __restrict__ numRoots,
                                                      int2* __restrict__ edges,
                                                      int* __restrict__ edgeCnt) {
  int inst = blockIdx.x;
  if (numRoots[inst] <= 1) return;
  unsigned short* compI = comp + (size_t)inst * N_PTS;
  unsigned long long* bkI = bestKey + (size_t)inst * N_PTS;
  edges += (size_t)inst * NEDGE;

  __shared__ unsigned short comp_s[N_PTS];           // 8 KB
  __shared__ unsigned short parent_s[N_PTS];         // 8 KB
  __shared__ unsigned long long key_s[N_PTS];        // 32 KB
  __shared__ int wtot[16], wbase[16];
  __shared__ int rootCnt, changed;
  int tid = threadIdx.x, lane = tid & 63, w = tid >> 6;
  if (tid == 0) rootCnt = 0;
  for (int i = tid; i < N_PTS / 8; i += 1024)
    ((uint4*)comp_s)[i] = ((const uint4*)compI)[i];
  for (int i = tid; i < N_PTS / 2; i += 1024)
    ((uint4*)key_s)[i] = ((const uint4*)bkI)[i];
  __syncthreads();

  int cnt = 0;
  int2 ebuf[4];
#pragma unroll
  for (int k = 0; k < 4; ++k) {
    int c = tid + k * 1024;
    unsigned short p = (unsigned short)c;
    if (comp_s[c] == c) {  // root
      unsigned long long key = key_s[c];
      bkI[c] = ~0ULL;  // reset (plain store; visible next dispatch)
      if (key != ~0ULL) {
        int lo = (int)((key >> 12) & 0xFFF), hi = (int)(key & 0xFFF);
        int c2 = (comp_s[lo] == c) ? comp_s[hi] : comp_s[lo];
        bool mutual = (key_s[c2] == key);
        bool add;
        if (mutual) {
          if (c < c2) add = true;  // smaller root keeps the shared edge, stays root
          else { p = (unsigned short)c2; add = false; }
        } else { p = (unsigned short)c2; add = true; }
        if (add) ebuf[cnt++] = make_int2(lo, hi);
      }
    }
    parent_s[c] = p;
  }
  // wave-inclusive scan of edge counts, then 16-entry serial scan
  int ws = cnt;
#pragma unroll
  for (int off = 1; off < 64; off <<= 1) {
    int v = __shfl_up(ws, off);
    if (lane >= off) ws += v;
  }
  if (lane == 63) wtot[w] = ws;
  __syncthreads();
  if (tid == 0) {
    int acc = edgeCnt[inst];
    for (int k = 0; k < 16; ++k) { wbase[k] = acc; acc += wtot[k]; }
    edgeCnt[inst] = acc;
  }
  __syncthreads();
  int base = wbase[w] + ws - cnt;
  for (int k = 0; k < cnt; ++k)
    if (base + k < NEDGE) edges[base + k] = ebuf[k];
  // adaptive pointer jumping (monotone in-place races benign; exits on fixpoint)
  for (int it = 0; it < 12; ++it) {
    if (tid == 0) changed = 0;
    __syncthreads();
    int any = 0;
#pragma unroll
    for (int k = 0; k < 4; ++k) {
      int c = tid + k * 1024;
      unsigned short p = parent_s[c];
      unsigned short pp = parent_s[p];
      if (pp != p) { parent_s[c] = pp; any = 1; }
    }
    if (any) changed = 1;
    __syncthreads();
    if (!changed) break;
  }
  int local = 0;
#pragma unroll
  for (int k = 0; k < 4; ++k) {
    int c = tid + k * 1024;
    unsigned short old = comp_s[c];
    if (old == (unsigned short)c && parent_s[c] == (unsigned short)c) local++;
    compI[c] = parent_s[old];
  }
  for (int off = 32; off > 0; off >>= 1) local += __shfl_down(local, off);
  if (lane == 0) atomicAdd(&rootCnt, local);
  __syncthreads();
  if (tid == 0) numRoots[inst] = rootCnt;
}

// ---- fused topo loss + finalize: ONE block. Gather u16 d^2, sqrt at use,
// block-reduce, broadcast topo, update all 4096 outputs. ----
__global__ __launch_bounds__(1024) void loss_final_kernel(const unsigned short* __restrict__ dD,
                                                          const unsigned short* __restrict__ dL,
                                                          const int2* __restrict__ edges_all,
                                                          const unsigned int* __restrict__ maxbits,
                                                          const unsigned int* __restrict__ normbits,
                                                          const float* __restrict__ latent_norm,
                                                          float* __restrict__ out) {
  int tid = threadIdx.x, lane = tid & 63, w = tid >> 6;
  float fac2D = (4.0f * __uint_as_float(normbits[0]) + 1e-12f) * (1.0f / 65535.0f);
  float fac2L = (4.0f * __uint_as_float(normbits[1]) + 1e-12f) * (1.0f / 65535.0f);
  float inv_md = 1.0f / sqrtf(__uint_as_float(*maxbits));  // maxbits = max d^2
  float inv_ln = 1.0f / latent_norm[0];
  float v0 = 0.f, v1 = 0.f;
#pragma unroll
  for (int k = 0; k < 8; ++k) {
    int e = tid + k * 1024;
    if (e >= 2 * NEDGE) break;
    int2 ed = edges_all[e];
    int i = ed.x & (N_PTS - 1), j = ed.y & (N_PTS - 1);
    float dd = sqrtf((float)dD[(size_t)i * N_PTS + j] * fac2D) * inv_md;
    float ld = sqrtf((float)dL[(size_t)i * N_PTS + j] * fac2L) * inv_ln;
    float df = dd - ld;
    if (e < NEDGE) v0 += df * df; else v1 += df * df;
  }
  for (int off = 32; off > 0; off >>= 1) {
    v0 += __shfl_down(v0, off);
    v1 += __shfl_down(v1, off);
  }
  __shared__ float s0[16], s1[16];
  __shared__ float topo_s;
  if (lane == 0) { s0[w] = v0; s1[w] = v1; }
  __syncthreads();
  if (tid == 0) {
    float t0 = 0.f, t1 = 0.f;
    for (int k = 0; k < 16; ++k) { t0 += s0[k]; t1 += s1[k]; }
    topo_s = 0.5f * (t0 + t1) * (1.0f / NEDGE);  // REG_LAMBDA = 0.5
  }
  __syncthreads();
  float add = topo_s;
#pragma unroll
  for (int k = 0; k < 4; ++k) out[tid + k * 1024] += add;
}

extern "C" void kernel_launch(void* const* d_in, const int* in_sizes, int n_in,
                              void* d_out, int out_size, void* d_ws, size_t ws_size,
                              hipStream_t stream) {
  const float* y_true = (const float*)d_in[0];
  const float* latent = (const float*)d_in[1];
  const float* y_pred = (const float*)d_in[2];
  const float* latent_norm = (const float*)d_in[3];
  float* out = (float*)d_out;
  char* ws = (char*)d_ws;

  const size_t MAT16 = (size_t)N_PTS * N_PTS * 2;  // 32 MB per u16 matrix
  size_t off = 0;
  unsigned short* dD = (unsigned short*)(ws + off); off += MAT16;
  unsigned short* dL = (unsigned short*)(ws + off); off += MAT16;
  unsigned short* Xb = (unsigned short*)(ws + off); off += (size_t)N_PTS * DD * 2;
  unsigned short* Lb = (unsigned short*)(ws + off); off += (size_t)N_PTS * DL * 2;
  float* sqD = (float*)(ws + off); off += (size_t)N_PTS * 4;
  float* sqL = (float*)(ws + off); off += (size_t)N_PTS * 4;
  int2* edges = (int2*)(ws + off); off += (size_t)2 * NEDGE * 8 + 16;
  unsigned long long* bestKey = (unsigned long long*)(ws + off); off += (size_t)2 * N_PTS * 8;
  unsigned short* comp = (unsigned short*)(ws + off); off += (size_t)2 * N_PTS * 2;
  unsigned int* segKey = (unsigned int*)(ws + off); off += (size_t)2 * N_PTS * 64 * 4;
  int* numRoots = (int*)(ws + off); off += 256;
  int* edgeCnt = numRoots + 2;
  unsigned int* maxbits = (unsigned int*)(edgeCnt + 2);
  float* sums = (float*)(maxbits + 1);
  unsigned int* normbits = (unsigned int*)(sums + 2);

  ae_sql_kernel<<<N_PTS + N_PTS / 4, 256, 0, stream>>>(y_true, y_pred, latent, out,
                                                       sqD, sqL, Xb, Lb);
  boruvka_init<<<N_PTS / 256, 256, 0, stream>>>(comp, bestKey, numRoots, edgeCnt,
                                                sqD, sqL, normbits, maxbits, sums);

  int tri = NT * (NT + 1) / 2;  // 528
  dist_mfma<<<dim3(tri, 2), 256, 0, stream>>>(Xb, Lb, sqD, sqL, dD, dL, normbits, maxbits);

  boruvka_scan0<<<dim3(N_PTS / 4, 2), 256, 0, stream>>>(dD, dL, segKey, bestKey);
  boruvka_merge<<<2, 1024, 0, stream>>>(comp, bestKey, numRoots, edges, edgeCnt);
  for (int r = 1; r < B_ROUNDS; ++r) {
    boruvka_scan<<<dim3(N_PTS / 4, 2), 256, 0, stream>>>(dD, dL, segKey, comp, bestKey,
                                                         numRoots);
    boruvka_merge<<<2, 1024, 0, stream>>>(comp, bestKey, numRoots, edges, edgeCnt);
  }

  loss_final_kernel<<<1, 1024, 0, stream>>>(dD, dL, edges, maxbits, normbits,
                                            latent_norm, out);
}

// Round 15
// 255.316 us; speedup vs baseline: 1.0644x; 1.0644x over previous
//
#include <hip/hip_runtime.h>
#include <math.h>

#define N_PTS 4096
#define DD 1024
#define DL 64
#define NEDGE (N_PTS - 1)
#define B_ROUNDS 12
#define NT 32  // 4096/128 tiles per dim

typedef __attribute__((ext_vector_type(8))) short short8;
typedef __attribute__((ext_vector_type(4))) float floatx4;
typedef __attribute__((ext_vector_type(4))) unsigned short ushortx4;

__device__ __forceinline__ unsigned short f2bf(float f) {
  unsigned u = __float_as_uint(f);
  u = u + 0x7FFFu + ((u >> 16) & 1u);  // RNE
  return (unsigned short)(u >> 16);
}

// ---- fused: ae_loss + sqnorms + bf16 converts (blocks [0,4096) data, [4096,5120) latent)
__global__ __launch_bounds__(256) void ae_sql_kernel(const float* __restrict__ yt,
                                                     const float* __restrict__ yp,
                                                     const float* __restrict__ lat,
                                                     float* __restrict__ out,
                                                     float* __restrict__ sqD,
                                                     float* __restrict__ sqL,
                                                     unsigned short* __restrict__ Xb,
                                                     unsigned short* __restrict__ Lb) {
  int tid = threadIdx.x;
  if (blockIdx.x < N_PTS) {
    int row = blockIdx.x;
    const float4* a = (const float4*)(yt + (size_t)row * DD);
    const float4* b = (const float4*)(yp + (size_t)row * DD);
    float4 va = a[tid], vb = b[tid];
    ushortx4 o = {f2bf(va.x), f2bf(va.y), f2bf(va.z), f2bf(va.w)};
    *(ushortx4*)(Xb + (size_t)row * DD + tid * 4) = o;
    float e0 = va.x - vb.x, e1 = va.y - vb.y, e2 = va.z - vb.z, e3 = va.w - vb.w;
    float se = e0 * e0 + e1 * e1 + e2 * e2 + e3 * e3;
    float ss = va.x * va.x + va.y * va.y + va.z * va.z + va.w * va.w;
    for (int off = 32; off > 0; off >>= 1) {
      se += __shfl_down(se, off);
      ss += __shfl_down(ss, off);
    }
    __shared__ float sse[4], sss[4];
    int lane = tid & 63, w = tid >> 6;
    if (lane == 0) { sse[w] = se; sss[w] = ss; }
    __syncthreads();
    if (tid == 0) {
      out[row] = (sse[0] + sse[1] + sse[2] + sse[3]) * (1.0f / DD);
      sqD[row] = sss[0] + sss[1] + sss[2] + sss[3];
    }
  } else {
    int row = (blockIdx.x - N_PTS) * 4 + (tid >> 6);
    int lane = tid & 63;
    float v = lat[(size_t)row * DL + lane];
    Lb[(size_t)row * DL + lane] = f2bf(v);
    float s = v * v;
    for (int off = 32; off > 0; off >>= 1) s += __shfl_down(s, off);
    if (lane == 0) sqL[row] = s;
  }
}

// ------- init + fused norm + counter zeroing (R14-proven) -------
__global__ __launch_bounds__(256) void boruvka_init(unsigned short* __restrict__ comp,
                                                    unsigned long long* __restrict__ bestKey,
                                                    int* __restrict__ numRoots,
                                                    int* __restrict__ edgeCnt,
                                                    const float* __restrict__ sqD,
                                                    const float* __restrict__ sqL,
                                                    unsigned int* __restrict__ normbits,
                                                    unsigned int* __restrict__ maxbits,
                                                    float* __restrict__ sums) {
  int i = blockIdx.x * 256 + threadIdx.x;
  if (i < N_PTS) {
    comp[i] = (unsigned short)i;
    comp[N_PTS + i] = (unsigned short)i;
    bestKey[i] = ~0ULL;
    bestKey[N_PTS + i] = ~0ULL;
  }
  if (i == 0) {
    numRoots[0] = N_PTS; numRoots[1] = N_PTS;
    edgeCnt[0] = 0; edgeCnt[1] = 0;
    maxbits[0] = 0;
    sums[0] = 0.f; sums[1] = 0.f;
  }
  if (blockIdx.x < 2) {
    const float* s = blockIdx.x ? sqL : sqD;
    int tid = threadIdx.x;
    float m = 0.f;
#pragma unroll
    for (int k = 0; k < 16; ++k) m = fmaxf(m, s[tid + k * 256]);
    for (int off = 32; off > 0; off >>= 1) m = fmaxf(m, __shfl_down(m, off));
    __shared__ float sm[4];
    int lane = tid & 63, w = tid >> 6;
    if (lane == 0) sm[w] = m;
    __syncthreads();
    if (tid == 0)
      normbits[blockIdx.x] = __float_as_uint(fmaxf(fmaxf(sm[0], sm[1]), fmaxf(sm[2], sm[3])));
  }
}

// ---------------- bf16 MFMA distance gemm -> scaled-u16 D-SQUARED matrices ----------
// (R14-proven: d^2 is monotone -> same MST; drops 16K sqrts from the epilogue.)
__global__ __launch_bounds__(256) void dist_mfma(const unsigned short* __restrict__ Xb,
                                                 const unsigned short* __restrict__ Lb,
                                                 const float* __restrict__ sqD,
                                                 const float* __restrict__ sqL,
                                                 unsigned short* __restrict__ dD,
                                                 unsigned short* __restrict__ dL,
                                                 const unsigned int* __restrict__ normbits,
                                                 unsigned int* __restrict__ maxbits) {
  int inst = blockIdx.y;
  const unsigned short* X = inst ? Lb : Xb;
  const float* sq = inst ? sqL : sqD;
  unsigned short* dist = inst ? dL : dD;
  int K = inst ? DL : DD;
  float scale2 = 65535.0f / (4.0f * __uint_as_float(normbits[inst]) + 1e-12f);

  int bi = 0, rem = blockIdx.x, span = NT;  // triangular decode, bi <= bj
  while (rem >= span) { rem -= span; ++bi; --span; }
  int bj = bi + rem;
  int row0 = bi * 128, col0 = bj * 128;

  __shared__ short As[128 * 40];
  __shared__ short Bs[128 * 40];
  int tid = threadIdx.x;
  int wave = tid >> 6, lane = tid & 63;
  int m = lane & 15, q = lane >> 4;
  int rw = (wave >> 1) * 64, cw = (wave & 1) * 64;

  floatx4 acc[4][4];
#pragma unroll
  for (int mi = 0; mi < 4; ++mi)
#pragma unroll
    for (int ni = 0; ni < 4; ++ni) acc[mi][ni] = {0.f, 0.f, 0.f, 0.f};

  int s0 = tid, s1 = tid + 256;
  int r0 = s0 >> 2, p0 = s0 & 3, r1 = s1 >> 2, p1 = s1 & 3;

  for (int k0 = 0; k0 < K; k0 += 32) {
    short8 a0 = *(const short8*)(X + (size_t)(row0 + r0) * K + k0 + p0 * 8);
    short8 a1 = *(const short8*)(X + (size_t)(row0 + r1) * K + k0 + p1 * 8);
    short8 b0 = *(const short8*)(X + (size_t)(col0 + r0) * K + k0 + p0 * 8);
    short8 b1 = *(const short8*)(X + (size_t)(col0 + r1) * K + k0 + p1 * 8);
    __syncthreads();
    *(short8*)&As[r0 * 40 + p0 * 8] = a0;
    *(short8*)&As[r1 * 40 + p1 * 8] = a1;
    *(short8*)&Bs[r0 * 40 + p0 * 8] = b0;
    *(short8*)&Bs[r1 * 40 + p1 * 8] = b1;
    __syncthreads();
    short8 aF[4], bF[4];
#pragma unroll
    for (int mi = 0; mi < 4; ++mi)
      aF[mi] = *(const short8*)&As[(rw + mi * 16 + m) * 40 + q * 8];
#pragma unroll
    for (int ni = 0; ni < 4; ++ni)
      bF[ni] = *(const short8*)&Bs[(cw + ni * 16 + m) * 40 + q * 8];
#pragma unroll
    for (int mi = 0; mi < 4; ++mi)
#pragma unroll
      for (int ni = 0; ni < 4; ++ni)
        acc[mi][ni] = __builtin_amdgcn_mfma_f32_16x16x32_bf16(aF[mi], bF[ni],
                                                              acc[mi][ni], 0, 0, 0);
  }

  float bmax = 0.f;  // max d^2
#pragma unroll
  for (int mi = 0; mi < 4; ++mi) {
    int i0 = row0 + rw + mi * 16 + q * 4;
    float s_i[4] = {sq[i0], sq[i0 + 1], sq[i0 + 2], sq[i0 + 3]};
#pragma unroll
    for (int ni = 0; ni < 4; ++ni) {
      int j = col0 + cw + ni * 16 + m;
      float sj = sq[j];
      ushortx4 tvec;
#pragma unroll
      for (int r = 0; r < 4; ++r) {
        float d2 = s_i[r] + sj - 2.f * acc[mi][ni][r];
        d2 = d2 > 0.f ? d2 : 0.f;
        bmax = fmaxf(bmax, d2);
        unsigned short u = (unsigned short)fminf(d2 * scale2, 65535.0f);
        dist[(size_t)(i0 + r) * N_PTS + j] = u;
        tvec[r] = u;
      }
      *(ushortx4*)&dist[(size_t)j * N_PTS + i0] = tvec;
    }
  }
  if (inst == 0) {
    for (int off = 32; off > 0; off >>= 1) bmax = fmaxf(bmax, __shfl_down(bmax, off));
    __shared__ float bm[4];
    if (lane == 0) bm[wave] = bmax;
    __syncthreads();
    if (tid == 0)
      atomicMax(maxbits, __float_as_uint(fmaxf(fmaxf(bm[0], bm[1]), fmaxf(bm[2], bm[3]))));
  }
}

// Round 0 scan fused with segmin (R11-proven): one 64MB pass -> segKey + plain bestKey.
__global__ __launch_bounds__(256) void boruvka_scan0(const unsigned short* __restrict__ dD,
                                                     const unsigned short* __restrict__ dL,
                                                     unsigned int* __restrict__ segKey,
                                                     unsigned long long* __restrict__ bestKey) {
  int inst = blockIdx.y;
  const unsigned short* dist = inst ? dL : dD;
  unsigned int* segK = segKey + (size_t)inst * N_PTS * 64;
  unsigned long long* bkI = bestKey + (size_t)inst * N_PTS;
  int tid = threadIdx.x, wave = tid >> 6, lane = tid & 63;
  int row = blockIdx.x * 4 + wave;
  const uint4* rowp = (const uint4*)(dist + (size_t)row * N_PTS);
  unsigned mk = 0xFFFFFFFFu, fk = 0xFFFFFFFFu;
  int colbase = lane * 64;
#pragma unroll
  for (int t = 0; t < 8; ++t) {
    uint4 v = rowp[lane * 8 + t];
    unsigned e[8] = {v.x & 0xFFFFu, v.x >> 16, v.y & 0xFFFFu, v.y >> 16,
                     v.z & 0xFFFFu, v.z >> 16, v.w & 0xFFFFu, v.w >> 16};
#pragma unroll
    for (int u = 0; u < 8; ++u) {
      int col = colbase + t * 8 + u;
      unsigned key = (e[u] << 12) | (unsigned)col;
      mk = min(mk, key);
      if (col != row) fk = min(fk, key);
    }
  }
  segK[(size_t)row * 64 + lane] = mk;
#pragma unroll
  for (int off = 32; off > 0; off >>= 1) fk = min(fk, __shfl_xor(fk, off));
  if (lane == 0) {
    unsigned dd16 = fk >> 12;
    int j = (int)(fk & 0xFFFu);
    int lo = row < j ? row : j, hi = row < j ? j : row;
    bkI[row] = ((unsigned long long)dd16 << 24) |
               ((unsigned long long)lo << 12) | (unsigned long long)hi;
  }
}

// Generic scan (rounds >= 1): segment-pruned, one row per wave.
__global__ __launch_bounds__(256) void boruvka_scan(const unsigned short* __restrict__ dD,
                                                    const unsigned short* __restrict__ dL,
                                                    const unsigned int* __restrict__ segKey,
                                                    const unsigned short* __restrict__ comp,
                                                    unsigned long long* __restrict__ bestKey,
                                                    const int* __restrict__ numRoots) {
  int inst = blockIdx.y;
  if (numRoots[inst] <= 1) return;
  const unsigned short* dist = inst ? dL : dD;
  const unsigned int* segK = segKey + (size_t)inst * N_PTS * 64;
  const unsigned short* compI = comp + (size_t)inst * N_PTS;
  unsigned long long* bkI = bestKey + (size_t)inst * N_PTS;
  int tid = threadIdx.x, wave = tid >> 6, lane = tid & 63;

  int row = blockIdx.x * 4 + wave;
  unsigned myc = compI[row];
  unsigned skey = segK[(size_t)row * 64 + lane];
#pragma unroll
  for (int k = 2; k <= 64; k <<= 1)
#pragma unroll
    for (int j = k >> 1; j > 0; j >>= 1) {
      unsigned p = __shfl_xor(skey, j);
      unsigned mn = min(skey, p), mx = max(skey, p);
      skey = (((lane & k) == 0) == ((lane & j) == 0)) ? mn : mx;
    }
  unsigned best = 0xFFFFFFFFu;
  const unsigned short* rowp = dist + (size_t)row * N_PTS;
  int i = 0;
  while (i < 64) {
    unsigned k0 = __shfl(skey, i);
    if (k0 >= best) break;
    unsigned k1 = (i < 63) ? __shfl(skey, i + 1) : 0xFFFFFFFFu;
    int b0 = (int)(k0 & 0xFC0u);
    unsigned d0v = rowp[b0 + lane];
    unsigned c0v = compI[b0 + lane];
    unsigned cand = (c0v != myc) ? ((d0v << 12) | (unsigned)(b0 + lane)) : 0xFFFFFFFFu;
    if (k1 < best) {
      int b1 = (int)(k1 & 0xFC0u);
      unsigned d1v = rowp[b1 + lane];
      unsigned c1v = compI[b1 + lane];
      unsigned c2 = (c1v != myc) ? ((d1v << 12) | (unsigned)(b1 + lane)) : 0xFFFFFFFFu;
      cand = min(cand, c2);
    }
#pragma unroll
    for (int off = 32; off > 0; off >>= 1) cand = min(cand, __shfl_xor(cand, off));
    best = min(best, cand);
    i += 2;
  }
  if (lane == 0 && best != 0xFFFFFFFFu) {
    unsigned dd16 = best >> 12;
    int j = (int)(best & 0xFFFu);
    int lo = row < j ? row : j, hi = row < j ? j : row;
    unsigned long long key40 = ((unsigned long long)dd16 << 24) |
                               ((unsigned long long)lo << 12) | (unsigned long long)hi;
    if (key40 < bkI[myc]) atomicMin(&bkI[myc], key40);  // bkI monotone in-dispatch
  }
}

// Merge (R12-proven): separate dispatch, plain cached loads, wave-shfl prefix
// scan + adaptive pointer jumping. One block per instance, 1024 threads.
__global__ __launch_bounds__(1024) void boruvka_merge(unsigned short* __restrict__ comp,
                                                      unsigned long long* __restrict__ bestKey,
                                                      int* __restrict__ numRoots,
                                                      int2* __restrict__ edges,
                                                      int* __restrict__ edgeCnt) {
  int inst = blockIdx.x;
  if (numRoots[inst] <= 1) return;
  unsigned short* compI = comp + (size_t)inst * N_PTS;
  unsigned long long* bkI = bestKey + (size_t)inst * N_PTS;
  edges += (size_t)inst * NEDGE;

  __shared__ unsigned short comp_s[N_PTS];           // 8 KB
  __shared__ unsigned short parent_s[N_PTS];         // 8 KB
  __shared__ unsigned long long key_s[N_PTS];        // 32 KB
  __shared__ int wtot[16], wbase[16];
  __shared__ int rootCnt, changed;
  int tid = threadIdx.x, lane = tid & 63, w = tid >> 6;
  if (tid == 0) rootCnt = 0;
  for (int i = tid; i < N_PTS / 8; i += 1024)
    ((uint4*)comp_s)[i] = ((const uint4*)compI)[i];
  for (int i = tid; i < N_PTS / 2; i += 1024)
    ((uint4*)key_s)[i] = ((const uint4*)bkI)[i];
  __syncthreads();

  int cnt = 0;
  int2 ebuf[4];
#pragma unroll
  for (int k = 0; k < 4; ++k) {
    int c = tid + k * 1024;
    unsigned short p = (unsigned short)c;
    if (comp_s[c] == c) {  // root
      unsigned long long key = key_s[c];
      bkI[c] = ~0ULL;  // reset (plain store; visible next dispatch)
      if (key != ~0ULL) {
        int lo = (int)((key >> 12) & 0xFFF), hi = (int)(key & 0xFFF);
        int c2 = (comp_s[lo] == c) ? comp_s[hi] : comp_s[lo];
        bool mutual = (key_s[c2] == key);
        bool add;
        if (mutual) {
          if (c < c2) add = true;  // smaller root keeps the shared edge, stays root
          else { p = (unsigned short)c2; add = false; }
        } else { p = (unsigned short)c2; add = true; }
        if (add) ebuf[cnt++] = make_int2(lo, hi);
      }
    }
    parent_s[c] = p;
  }
  // wave-inclusive scan of edge counts, then 16-entry serial scan
  int ws = cnt;
#pragma unroll
  for (int off = 1; off < 64; off <<= 1) {
    int v = __shfl_up(ws, off);
    if (lane >= off) ws += v;
  }
  if (lane == 63) wtot[w] = ws;
  __syncthreads();
  if (tid == 0) {
    int acc = edgeCnt[inst];
    for (int k = 0; k < 16; ++k) { wbase[k] = acc; acc += wtot[k]; }
    edgeCnt[inst] = acc;
  }
  __syncthreads();
  int base = wbase[w] + ws - cnt;
  for (int k = 0; k < cnt; ++k)
    if (base + k < NEDGE) edges[base + k] = ebuf[k];
  // adaptive pointer jumping (monotone in-place races benign; exits on fixpoint)
  for (int it = 0; it < 12; ++it) {
    if (tid == 0) changed = 0;
    __syncthreads();
    int any = 0;
#pragma unroll
    for (int k = 0; k < 4; ++k) {
      int c = tid + k * 1024;
      unsigned short p = parent_s[c];
      unsigned short pp = parent_s[p];
      if (pp != p) { parent_s[c] = pp; any = 1; }
    }
    if (any) changed = 1;
    __syncthreads();
    if (!changed) break;
  }
  int local = 0;
#pragma unroll
  for (int k = 0; k < 4; ++k) {
    int c = tid + k * 1024;
    unsigned short old = comp_s[c];
    if (old == (unsigned short)c && parent_s[c] == (unsigned short)c) local++;
    compI[c] = parent_s[old];
  }
  for (int off = 32; off > 0; off >>= 1) local += __shfl_down(local, off);
  if (lane == 0) atomicAdd(&rootCnt, local);
  __syncthreads();
  if (tid == 0) numRoots[inst] = rootCnt;
}

// ---------------- topo losses gathered from the u16 d^2 matrices (32 blocks:
// spreads the 16K scattered gathers across CUs — R14's 1-block fusion serialized
// them on one CU and regressed ~25us) ----------------
__global__ __launch_bounds__(256) void loss_kernel(const unsigned short* __restrict__ dD,
                                                   const unsigned short* __restrict__ dL,
                                                   const int2* __restrict__ edges_all,
                                                   const unsigned int* __restrict__ maxbits,
                                                   const unsigned int* __restrict__ normbits,
                                                   const float* __restrict__ latent_norm,
                                                   float* __restrict__ sums) {
  int tid = threadIdx.x;
  int e = blockIdx.x * 256 + tid;
  float fac2D = (4.0f * __uint_as_float(normbits[0]) + 1e-12f) * (1.0f / 65535.0f);
  float fac2L = (4.0f * __uint_as_float(normbits[1]) + 1e-12f) * (1.0f / 65535.0f);
  float inv_md = 1.0f / sqrtf(__uint_as_float(*maxbits));  // maxbits = max d^2
  float inv_ln = 1.0f / latent_norm[0];
  float v0 = 0.f, v1 = 0.f;
  if (e < 2 * NEDGE) {
    int2 ed = edges_all[e];
    int i = ed.x & (N_PTS - 1), j = ed.y & (N_PTS - 1);
    float dd = sqrtf((float)dD[(size_t)i * N_PTS + j] * fac2D) * inv_md;
    float ld = sqrtf((float)dL[(size_t)i * N_PTS + j] * fac2L) * inv_ln;
    float df = dd - ld;
    if (e < NEDGE) v0 = df * df; else v1 = df * df;
  }
  for (int off = 32; off > 0; off >>= 1) {
    v0 += __shfl_down(v0, off);
    v1 += __shfl_down(v1, off);
  }
  __shared__ float s0[4], s1[4];
  int lane = tid & 63, w = tid >> 6;
  if (lane == 0) { s0[w] = v0; s1[w] = v1; }
  __syncthreads();
  if (tid == 0) {
    float t0 = s0[0] + s0[1] + s0[2] + s0[3];
    float t1 = s1[0] + s1[1] + s1[2] + s1[3];
    if (t0 != 0.f) atomicAdd(&sums[0], t0);
    if (t1 != 0.f) atomicAdd(&sums[1], t1);
  }
}

__global__ __launch_bounds__(256) void finalize_kernel(float* __restrict__ out,
                                                       const float* __restrict__ sums) {
  int i = blockIdx.x * blockDim.x + threadIdx.x;
  float topo = (sums[0] + sums[1]) * (1.0f / NEDGE);
  out[i] += 0.5f * topo;  // REG_LAMBDA
}

extern "C" void kernel_launch(void* const* d_in, const int* in_sizes, int n_in,
                              void* d_out, int out_size, void* d_ws, size_t ws_size,
                              hipStream_t stream) {
  const float* y_true = (const float*)d_in[0];
  const float* latent = (const float*)d_in[1];
  const float* y_pred = (const float*)d_in[2];
  const float* latent_norm = (const float*)d_in[3];
  float* out = (float*)d_out;
  char* ws = (char*)d_ws;

  const size_t MAT16 = (size_t)N_PTS * N_PTS * 2;  // 32 MB per u16 matrix
  size_t off = 0;
  unsigned short* dD = (unsigned short*)(ws + off); off += MAT16;
  unsigned short* dL = (unsigned short*)(ws + off); off += MAT16;
  unsigned short* Xb = (unsigned short*)(ws + off); off += (size_t)N_PTS * DD * 2;
  unsigned short* Lb = (unsigned short*)(ws + off); off += (size_t)N_PTS * DL * 2;
  float* sqD = (float*)(ws + off); off += (size_t)N_PTS * 4;
  float* sqL = (float*)(ws + off); off += (size_t)N_PTS * 4;
  int2* edges = (int2*)(ws + off); off += (size_t)2 * NEDGE * 8 + 16;
  unsigned long long* bestKey = (unsigned long long*)(ws + off); off += (size_t)2 * N_PTS * 8;
  unsigned short* comp = (unsigned short*)(ws + off); off += (size_t)2 * N_PTS * 2;
  unsigned int* segKey = (unsigned int*)(ws + off); off += (size_t)2 * N_PTS * 64 * 4;
  int* numRoots = (int*)(ws + off); off += 256;
  int* edgeCnt = numRoots + 2;
  unsigned int* maxbits = (unsigned int*)(edgeCnt + 2);
  float* sums = (float*)(maxbits + 1);
  unsigned int* normbits = (unsigned int*)(sums + 2);

  ae_sql_kernel<<<N_PTS + N_PTS / 4, 256, 0, stream>>>(y_true, y_pred, latent, out,
                                                       sqD, sqL, Xb, Lb);
  boruvka_init<<<N_PTS / 256, 256, 0, stream>>>(comp, bestKey, numRoots, edgeCnt,
                                                sqD, sqL, normbits, maxbits, sums);

  int tri = NT * (NT + 1) / 2;  // 528
  dist_mfma<<<dim3(tri, 2), 256, 0, stream>>>(Xb, Lb, sqD, sqL, dD, dL, normbits, maxbits);

  boruvka_scan0<<<dim3(N_PTS / 4, 2), 256, 0, stream>>>(dD, dL, segKey, bestKey);
  boruvka_merge<<<2, 1024, 0, stream>>>(comp, bestKey, numRoots, edges, edgeCnt);
  for (int r = 1; r < B_ROUNDS; ++r) {
    boruvka_scan<<<dim3(N_PTS / 4, 2), 256, 0, stream>>>(dD, dL, segKey, comp, bestKey,
                                                         numRoots);
    boruvka_merge<<<2, 1024, 0, stream>>>(comp, bestKey, numRoots, edges, edgeCnt);
  }

  loss_kernel<<<32, 256, 0, stream>>>(dD, dL, edges, maxbits, normbits, latent_norm, sums);
  finalize_kernel<<<N_PTS / 256, 256, 0, stream>>>(out, sums);
}